// Round 1
// baseline (1452.366 us; speedup 1.0000x reference)
//
#include <hip/hip_runtime.h>

// d_out layout: gcn_users [U][192] then gcn_items [I][192]
//   cols 0:64   = embedding
//   cols 64:128 = gcn1
//   cols 128:192= gcn2

// Copy src[row][0:64] into dst[row][0:64] and dst[row][64:128] (float4 lanes).
__global__ void init_dup_kernel(const float4* __restrict__ src,
                                float4* __restrict__ dst,
                                int nrows)
{
    int gid = blockIdx.x * blockDim.x + threadIdx.x;
    if (gid >= nrows * 16) return;
    int row = gid >> 4;
    int c   = gid & 15;
    float4 v = src[gid];
    dst[row * 48 + c]      = v;
    dst[row * 48 + 16 + c] = v;
}

// Copy cols [64:128) -> [128:192) within the output buffer (float4 units).
__global__ void copy_col_kernel(float4* __restrict__ buf, int nrows)
{
    int gid = blockIdx.x * blockDim.x + threadIdx.x;
    if (gid >= nrows * 16) return;
    int row = gid >> 4;
    int c   = gid & 15;
    buf[row * 48 + 32 + c] = buf[row * 48 + 16 + c];
}

// One thread per (edge, feature). Both SpMMs (ui and iu) fused: each edge
// contributes to out_u[edge_user] and out_i[edge_item].
__global__ void spmm_kernel(const int*   __restrict__ edge_user,
                            const int*   __restrict__ edge_item,
                            const float* __restrict__ ui_vals,
                            const float* __restrict__ iu_vals,
                            const float* __restrict__ src_u, int src_u_stride,
                            const float* __restrict__ src_i, int src_i_stride,
                            float* __restrict__ out_u,
                            float* __restrict__ out_i,
                            int dst_col, int E)
{
    int gid = blockIdx.x * blockDim.x + threadIdx.x;
    if (gid >= E * 64) return;
    int e = gid >> 6;
    int f = gid & 63;
    int u = edge_user[e];
    int i = edge_item[e];
    float a = ui_vals[e];
    float b = iu_vals[e];
    float xi = src_i[i * src_i_stride + f];   // ui: out_u[u] += a * x_i[i]
    float xu = src_u[u * src_u_stride + f];   // iu: out_i[i] += b * x_u[u]
    unsafeAtomicAdd(&out_u[u * 192 + dst_col + f], a * xi);
    unsafeAtomicAdd(&out_i[i * 192 + dst_col + f], b * xu);
}

extern "C" void kernel_launch(void* const* d_in, const int* in_sizes, int n_in,
                              void* d_out, int out_size, void* d_ws, size_t ws_size,
                              hipStream_t stream)
{
    const float* emb_u   = (const float*)d_in[0];
    const float* emb_i   = (const float*)d_in[1];
    const float* ui_vals = (const float*)d_in[2];
    const float* iu_vals = (const float*)d_in[3];
    const int*   e_user  = (const int*)d_in[4];
    const int*   e_item  = (const int*)d_in[5];

    const int F = 64;
    const int U = in_sizes[0] / F;
    const int I = in_sizes[1] / F;
    const int E = in_sizes[4];

    float* out_u = (float*)d_out;            // [U][192]
    float* out_i = out_u + (size_t)U * 192;  // [I][192]

    const int BLK = 256;
    int grid_u  = (U * 16 + BLK - 1) / BLK;
    int grid_i  = (I * 16 + BLK - 1) / BLK;
    long long spmm_threads = (long long)E * 64;
    int grid_e  = (int)((spmm_threads + BLK - 1) / BLK);

    // Stage 0: out[:,0:64] = emb; out[:,64:128] = emb (residual for gcn1).
    init_dup_kernel<<<grid_u, BLK, 0, stream>>>((const float4*)emb_u, (float4*)out_u, U);
    init_dup_kernel<<<grid_i, BLK, 0, stream>>>((const float4*)emb_i, (float4*)out_i, I);

    // Stage 1: gcn1 += spmm(emb)
    spmm_kernel<<<grid_e, BLK, 0, stream>>>(e_user, e_item, ui_vals, iu_vals,
                                            emb_u, 64, emb_i, 64,
                                            out_u, out_i, 64, E);

    // Stage 2 init: gcn2 = gcn1 (residual).
    copy_col_kernel<<<grid_u, BLK, 0, stream>>>((float4*)out_u, U);
    copy_col_kernel<<<grid_i, BLK, 0, stream>>>((float4*)out_i, I);

    // Stage 2: gcn2 += spmm(gcn1)   (gcn1 lives at col 64, stride 192)
    spmm_kernel<<<grid_e, BLK, 0, stream>>>(e_user, e_item, ui_vals, iu_vals,
                                            out_u + 64, 192, out_i + 64, 192,
                                            out_u, out_i, 128, E);
}

// Round 2
// 705.766 us; speedup vs baseline: 2.0579x; 2.0579x over previous
//
#include <hip/hip_runtime.h>

// d_out layout: gcn_users [U][192] then gcn_items [I][192]
//   cols 0:64 = emb, 64:128 = gcn1, 128:192 = gcn2
//
// Strategy: build CSR (user-major + item-major) in d_ws each launch, then
// gather-style SpMM: one wave per output row, lane = feature, accumulate in
// registers, single coalesced store. No output atomics.

// ---------------- CSR build ----------------

__global__ void count_kernel(const int* __restrict__ eu, const int* __restrict__ ei,
                             int* __restrict__ du, int* __restrict__ di, int E)
{
    int e = blockIdx.x * blockDim.x + threadIdx.x;
    if (e >= E) return;
    atomicAdd(&du[eu[e]], 1);
    atomicAdd(&di[ei[e]], 1);
}

// Exclusive scan within each 1024-block; block totals to bsums (if non-null).
__global__ void scan_block_kernel(const int* __restrict__ in, int n,
                                  int* __restrict__ out, int* __restrict__ bsums)
{
    __shared__ int tmp[1024];
    int idx = blockIdx.x * 1024 + threadIdx.x;
    int x = (idx < n) ? in[idx] : 0;
    tmp[threadIdx.x] = x;
    __syncthreads();
    #pragma unroll
    for (int off = 1; off < 1024; off <<= 1) {
        int t = (threadIdx.x >= off) ? tmp[threadIdx.x - off] : 0;
        __syncthreads();
        tmp[threadIdx.x] += t;
        __syncthreads();
    }
    if (idx < n) out[idx] = tmp[threadIdx.x] - x;
    if (threadIdx.x == 1023 && bsums) bsums[blockIdx.x] = tmp[1023];
}

__global__ void scan_fixup_kernel(int* __restrict__ rp, const int* __restrict__ bscan,
                                  int n, int total)
{
    int idx = blockIdx.x * blockDim.x + threadIdx.x;
    if (idx < n) rp[idx] += bscan[idx >> 10];
    else if (idx == n) rp[n] = total;
}

__global__ void copy_int_kernel(const int* __restrict__ src, int* __restrict__ dst, int n)
{
    int idx = blockIdx.x * blockDim.x + threadIdx.x;
    if (idx < n) dst[idx] = src[idx];
}

__global__ void scatter_kernel(const int* __restrict__ eu, const int* __restrict__ ei,
                               const float* __restrict__ uiv, const float* __restrict__ iuv,
                               int* __restrict__ wpu, int* __restrict__ wpi,
                               int* __restrict__ cu, float* __restrict__ vu,
                               int* __restrict__ ci, float* __restrict__ vi, int E)
{
    int e = blockIdx.x * blockDim.x + threadIdx.x;
    if (e >= E) return;
    int u = eu[e], i = ei[e];
    int pu = atomicAdd(&wpu[u], 1);
    cu[pu] = i;
    vu[pu] = uiv[e];
    int pi = atomicAdd(&wpi[i], 1);
    ci[pi] = u;
    vi[pi] = iuv[e];
}

// ---------------- gather SpMM ----------------
// One wave per row; lane = feature. out[row*192 + dst_col + f] =
//   resid[row*rstride + f] + sum_e vals[e] * src[cols[e]*sstride + f]
template <int COPY_EMB>
__global__ __launch_bounds__(256) void spmm_gather(
    const int* __restrict__ rp, const int* __restrict__ cols,
    const float* __restrict__ vals,
    const float* __restrict__ src, int sstride,
    const float* __restrict__ resid, int rstride,
    float* __restrict__ out, int dst_col,
    const float* __restrict__ emb, int nrows)
{
    int wid = (blockIdx.x * blockDim.x + threadIdx.x) >> 6;
    int f   = threadIdx.x & 63;
    if (wid >= nrows) return;
    int beg = rp[wid], end = rp[wid + 1];
    float a0 = 0.f, a1 = 0.f, a2 = 0.f, a3 = 0.f;
    int e = beg;
    for (; e + 3 < end; e += 4) {
        float v0 = vals[e],     v1 = vals[e + 1];
        float v2 = vals[e + 2], v3 = vals[e + 3];
        int   c0 = cols[e],     c1 = cols[e + 1];
        int   c2 = cols[e + 2], c3 = cols[e + 3];
        a0 += v0 * src[c0 * sstride + f];
        a1 += v1 * src[c1 * sstride + f];
        a2 += v2 * src[c2 * sstride + f];
        a3 += v3 * src[c3 * sstride + f];
    }
    for (; e < end; ++e)
        a0 += vals[e] * src[cols[e] * sstride + f];
    float acc = (a0 + a1) + (a2 + a3);
    acc += resid[wid * rstride + f];
    out[wid * 192 + dst_col + f] = acc;
    if (COPY_EMB) out[wid * 192 + f] = emb[wid * 64 + f];
}

// ---------------- fallback (round-1 atomic path) ----------------

__global__ void init_dup_kernel(const float4* __restrict__ src,
                                float4* __restrict__ dst, int nrows)
{
    int gid = blockIdx.x * blockDim.x + threadIdx.x;
    if (gid >= nrows * 16) return;
    int row = gid >> 4, c = gid & 15;
    float4 v = src[gid];
    dst[row * 48 + c]      = v;
    dst[row * 48 + 16 + c] = v;
}

__global__ void copy_col_kernel(float4* __restrict__ buf, int nrows)
{
    int gid = blockIdx.x * blockDim.x + threadIdx.x;
    if (gid >= nrows * 16) return;
    int row = gid >> 4, c = gid & 15;
    buf[row * 48 + 32 + c] = buf[row * 48 + 16 + c];
}

__global__ void spmm_atomic(const int* __restrict__ edge_user,
                            const int* __restrict__ edge_item,
                            const float* __restrict__ ui_vals,
                            const float* __restrict__ iu_vals,
                            const float* __restrict__ src_u, int su,
                            const float* __restrict__ src_i, int si,
                            float* __restrict__ out_u, float* __restrict__ out_i,
                            int dst_col, int E)
{
    int gid = blockIdx.x * blockDim.x + threadIdx.x;
    if (gid >= E * 64) return;
    int e = gid >> 6, f = gid & 63;
    int u = edge_user[e], i = edge_item[e];
    unsafeAtomicAdd(&out_u[u * 192 + dst_col + f], ui_vals[e] * src_i[i * si + f]);
    unsafeAtomicAdd(&out_i[i * 192 + dst_col + f], iu_vals[e] * src_u[u * su + f]);
}

extern "C" void kernel_launch(void* const* d_in, const int* in_sizes, int n_in,
                              void* d_out, int out_size, void* d_ws, size_t ws_size,
                              hipStream_t stream)
{
    const float* emb_u   = (const float*)d_in[0];
    const float* emb_i   = (const float*)d_in[1];
    const float* ui_vals = (const float*)d_in[2];
    const float* iu_vals = (const float*)d_in[3];
    const int*   e_user  = (const int*)d_in[4];
    const int*   e_item  = (const int*)d_in[5];

    const int F = 64;
    const int U = in_sizes[0] / F;
    const int I = in_sizes[1] / F;
    const int E = in_sizes[4];

    float* out_u = (float*)d_out;            // [U][192]
    float* out_i = out_u + (size_t)U * 192;  // [I][192]

    const int BLK = 256;
    size_t need = ((size_t)U + I + (U + 1) + (I + 1) + 512 + 4 * (size_t)E) * 4;

    if (ws_size >= need) {
        int*   wp_u   = (int*)d_ws;          // deg, later write-ptr
        int*   wp_i   = wp_u + U;
        int*   rp_u   = wp_i + I;            // U+1
        int*   rp_i   = rp_u + (U + 1);      // I+1
        int*   bsum   = rp_i + (I + 1);      // 256
        int*   bscan  = bsum + 256;          // 256
        int*   cols_u = bscan + 256;         // E
        float* vals_u = (float*)(cols_u + E);
        int*   cols_i = (int*)(vals_u + E);
        float* vals_i = (float*)(cols_i + E);

        // --- build CSR ---
        hipMemsetAsync(wp_u, 0, (size_t)(U + I) * 4, stream);
        count_kernel<<<(E + BLK - 1) / BLK, BLK, 0, stream>>>(e_user, e_item, wp_u, wp_i, E);

        int nb_u = (U + 1023) / 1024, nb_i = (I + 1023) / 1024;
        scan_block_kernel<<<nb_u, 1024, 0, stream>>>(wp_u, U, rp_u, bsum);
        scan_block_kernel<<<1, 1024, 0, stream>>>(bsum, nb_u, bscan, nullptr);
        scan_fixup_kernel<<<(U + 1 + BLK - 1) / BLK, BLK, 0, stream>>>(rp_u, bscan, U, E);
        scan_block_kernel<<<nb_i, 1024, 0, stream>>>(wp_i, I, rp_i, bsum);
        scan_block_kernel<<<1, 1024, 0, stream>>>(bsum, nb_i, bscan, nullptr);
        scan_fixup_kernel<<<(I + 1 + BLK - 1) / BLK, BLK, 0, stream>>>(rp_i, bscan, I, E);

        copy_int_kernel<<<(U + BLK - 1) / BLK, BLK, 0, stream>>>(rp_u, wp_u, U);
        copy_int_kernel<<<(I + BLK - 1) / BLK, BLK, 0, stream>>>(rp_i, wp_i, I);
        scatter_kernel<<<(E + BLK - 1) / BLK, BLK, 0, stream>>>(
            e_user, e_item, ui_vals, iu_vals, wp_u, wp_i,
            cols_u, vals_u, cols_i, vals_i, E);

        // --- stage 1: gcn1 = spmm(emb) + emb  (also copies emb into col 0) ---
        spmm_gather<1><<<(U * 64 + BLK - 1) / BLK, BLK, 0, stream>>>(
            rp_u, cols_u, vals_u, emb_i, 64, emb_u, 64, out_u, 64, emb_u, U);
        spmm_gather<1><<<(I * 64 + BLK - 1) / BLK, BLK, 0, stream>>>(
            rp_i, cols_i, vals_i, emb_u, 64, emb_i, 64, out_i, 64, emb_i, I);

        // --- stage 2: gcn2 = spmm(gcn1_other) + gcn1 ---
        spmm_gather<0><<<(U * 64 + BLK - 1) / BLK, BLK, 0, stream>>>(
            rp_u, cols_u, vals_u, out_i + 64, 192, out_u + 64, 192, out_u, 128, nullptr, U);
        spmm_gather<0><<<(I * 64 + BLK - 1) / BLK, BLK, 0, stream>>>(
            rp_i, cols_i, vals_i, out_u + 64, 192, out_i + 64, 192, out_i, 128, nullptr, I);
    } else {
        // fallback: atomic scatter path
        int grid_u = (U * 16 + BLK - 1) / BLK;
        int grid_i = (I * 16 + BLK - 1) / BLK;
        long long t = (long long)E * 64;
        int grid_e = (int)((t + BLK - 1) / BLK);
        init_dup_kernel<<<grid_u, BLK, 0, stream>>>((const float4*)emb_u, (float4*)out_u, U);
        init_dup_kernel<<<grid_i, BLK, 0, stream>>>((const float4*)emb_i, (float4*)out_i, I);
        spmm_atomic<<<grid_e, BLK, 0, stream>>>(e_user, e_item, ui_vals, iu_vals,
                                                emb_u, 64, emb_i, 64, out_u, out_i, 64, E);
        copy_col_kernel<<<grid_u, BLK, 0, stream>>>((float4*)out_u, U);
        copy_col_kernel<<<grid_i, BLK, 0, stream>>>((float4*)out_i, I);
        spmm_atomic<<<grid_e, BLK, 0, stream>>>(e_user, e_item, ui_vals, iu_vals,
                                                out_u + 64, 192, out_i + 64, 192,
                                                out_u, out_i, 128, E);
    }
}